// Round 5
// baseline (580.842 us; speedup 1.0000x reference)
//
#include <hip/hip_runtime.h>

// Problem constants: N=4096 agents, TOP_K=12, OBS_RADIUS=1.0
#define NN    4096
#define TOPK  12
#define NP    (NN * TOPK)        // 49152 pairs
// d_out layout (f32): out[0..NP), mask[NP..2NP), indices[2NP..) as (row, j)
#define OFF_MASK (NP)
#define OFF_IDX  (2 * NP)
#define RPB   4                  // rows per block
#define NPAIR (RPB * TOPK)       // 48 pairs per block

// ---------------------------------------------------------------------------
// Fused kernel: block = 1024 threads = 4 rows.
//  Phase A (topk, per 256-thread row-group): round-4's proven wave-local u64
//    pops (key = f32bits(s)<<32 | j : u64 order == (s,j) lexicographic).
//  Phase B (merge): waves 0..3 bitonic-sort each row's 48 candidates, write
//    mask+indices, park (j,d) in LDS.
//  Phase C (MLP 6->64->128->64->1): lanes 0..47 = pairs, 16 waves = neuron
//    chunks via readfirstlane -> all weight addrs scalar (s_load + v_fmac).
//    Activations via LDS [neuron][48] (2-way bank aliasing = free on CDNA4).
// Rationale: separate kernels ran latency-exposed (topk ~105us vs 41us HBM
// floor; mlp 60us vs 10.5us VALU floor at 3 blocks/CU, single generation).
// Fusion interleaves MLP VALU with topk memory stalls at 32 waves/CU.
// ---------------------------------------------------------------------------
__global__ __launch_bounds__(1024, 8) void fused_cbf(
        const float* __restrict__ x, const float* __restrict__ rp,
        const float* __restrict__ W1, const float* __restrict__ b1,
        const float* __restrict__ W2, const float* __restrict__ b2,
        const float* __restrict__ W3, const float* __restrict__ b3,
        const float* __restrict__ W4, const float* __restrict__ b4,
        float* __restrict__ out) {
    __shared__ unsigned long long cand[RPB][NPAIR];   // 1.5 KB
    __shared__ int   selj[RPB][TOPK];
    __shared__ float seld[RPB][TOPK];
    __shared__ float h1s[64 * NPAIR];                 // 12 KB
    __shared__ float h2s[128 * NPAIR];                // 24 KB
    __shared__ float p4s[16 * NPAIR];                 // 3 KB

    const int t    = threadIdx.x;
    const int r    = t >> 8;          // sub-row 0..3
    const int tt   = t & 255;         // thread-in-row
    const int lane = t & 63;
    const int wrow = tt >> 6;         // wave-in-row 0..3
    const int i    = blockIdx.x * RPB + r;
    const float4* x4 = (const float4*)x + (size_t)i * NN;

    // ---- Phase A: stage + wave-local top-12 pops (barrier-free) ----
    float s[16];
    #pragma unroll
    for (int k = 0; k < 16; ++k) {
        float4 v = x4[(k << 8) + tt];
        s[k] = v.x * v.x + v.y * v.y;
    }
    unsigned long long bk;
    {
        float bs = s[0]; int bj = tt;
        #pragma unroll
        for (int k = 1; k < 16; ++k) {
            int j = (k << 8) + tt;
            if (s[k] < bs) { bs = s[k]; bj = j; }
        }
        bk = ((unsigned long long)__float_as_uint(bs) << 32) | (unsigned)bj;
    }
    unsigned long long mykey = ~0ULL;
    for (int it = 0; it < TOPK; ++it) {
        unsigned long long vk = bk;
        #pragma unroll
        for (int off = 1; off < 64; off <<= 1) {
            unsigned long long ok = __shfl_xor(vk, off, 64);
            vk = (ok < vk) ? ok : vk;
        }
        if (lane == it) mykey = vk;
        int wj = (int)(vk & 0xffffffffULL);
        if ((wj & 63) == lane) {          // owner pops + recomputes proposal
            int kk = wj >> 8;
            #pragma unroll
            for (int k = 0; k < 16; ++k)
                if (k == kk) s[k] = 3.0e38f;
            float bs = s[0]; int bj = tt;
            #pragma unroll
            for (int k = 1; k < 16; ++k) {
                int j = (k << 8) + tt;
                if (s[k] < bs) { bs = s[k]; bj = j; }
            }
            bk = ((unsigned long long)__float_as_uint(bs) << 32) | (unsigned)bj;
        }
    }
    if (lane < TOPK) cand[r][wrow * TOPK + lane] = mykey;
    __syncthreads();

    // ---- Phase B: merge (waves 0..3 handle rows 0..3) ----
    {
        const int W = t >> 6;
        if (W < RPB) {
            unsigned long long key = (lane < NPAIR) ? cand[W][lane] : ~0ULL;
            #pragma unroll
            for (int k = 2; k <= 64; k <<= 1) {
                #pragma unroll
                for (int jj = k >> 1; jj >= 1; jj >>= 1) {
                    unsigned long long ok = __shfl_xor(key, jj, 64);
                    bool keepMin = ((lane & k) == 0) == ((lane & jj) == 0);
                    unsigned long long mn = (ok < key) ? ok : key;
                    unsigned long long mx = (ok < key) ? key : ok;
                    key = keepMin ? mn : mx;
                }
            }
            if (lane < TOPK) {
                int   j  = (int)(key & 0xffffffffULL);
                float ss = __uint_as_float((unsigned)(key >> 32));
                float d  = sqrtf(ss + 2.0e-4f);      // sqrt(sum(x[:2]^2+1e-4))
                int ii = blockIdx.x * RPB + W;
                int p  = ii * TOPK + lane;
                out[OFF_MASK + p]        = (d <= 1.0f) ? 1.0f : 0.0f;
                out[OFF_IDX + 2 * p]     = (float)ii;
                out[OFF_IDX + 2 * p + 1] = (float)j;
                selj[W][lane] = j;
                seld[W][lane] = d;
            }
        }
    }
    __syncthreads();

    // ---- Phase C: MLP. lanes 0..47 = pairs, 16 waves = neuron chunks ----
    const int  pl     = lane;
    const bool active = (pl < NPAIR);
    const int  ch     = __builtin_amdgcn_readfirstlane(t >> 6);  // SGPR 0..15
    const int  pls    = active ? pl : 0;       // clamped for LDS reads
    const int  pr     = pls / TOPK;
    const int  pk     = pls % TOPK;
    const int  jn     = selj[pr][pk];
    const float d     = seld[pr][pk];
    const int  ii     = blockIdx.x * RPB + pr;
    const float4 v = ((const float4*)x)[(size_t)ii * NN + jn];
    float xin[6];
    xin[0] = v.x; xin[1] = v.y; xin[2] = v.z; xin[3] = v.w;
    xin[4] = (ii == jn) ? 1.0f : 0.0f;
    xin[5] = d - rp[0];

    // L1: 4 neurons per wave
    #pragma unroll
    for (int q = 0; q < 4; ++q) {
        int m = ch * 4 + q;
        const float* w = W1 + m * 6;
        float a = b1[m];
        #pragma unroll
        for (int c = 0; c < 6; ++c) a += w[c] * xin[c];
        if (active) h1s[m * NPAIR + pl] = fmaxf(a, 0.0f);
    }
    __syncthreads();

    // L2: 8 neurons per wave, k streamed in parts of 16
    float acc[8];
    #pragma unroll
    for (int q = 0; q < 8; ++q) acc[q] = b2[ch * 8 + q];
    for (int part = 0; part < 4; ++part) {
        float h1r[16];
        #pragma unroll
        for (int k = 0; k < 16; ++k) h1r[k] = h1s[(part * 16 + k) * NPAIR + pls];
        #pragma unroll
        for (int q = 0; q < 8; ++q) {
            const float* w = W2 + (ch * 8 + q) * 64 + part * 16;   // scalar
            #pragma unroll
            for (int k = 0; k < 16; ++k) acc[q] += w[k] * h1r[k];
        }
    }
    #pragma unroll
    for (int q = 0; q < 8; ++q)
        if (active) h2s[(ch * 8 + q) * NPAIR + pl] = fmaxf(acc[q], 0.0f);
    __syncthreads();

    // L3: 4 neurons per wave, k streamed in parts of 16; + L4 partial
    float h3[4];
    #pragma unroll
    for (int q = 0; q < 4; ++q) h3[q] = b3[ch * 4 + q];
    for (int part = 0; part < 8; ++part) {
        float h2r[16];
        #pragma unroll
        for (int k = 0; k < 16; ++k) h2r[k] = h2s[(part * 16 + k) * NPAIR + pls];
        #pragma unroll
        for (int q = 0; q < 4; ++q) {
            const float* w = W3 + (ch * 4 + q) * 128 + part * 16;  // scalar
            #pragma unroll
            for (int k = 0; k < 16; ++k) h3[q] += w[k] * h2r[k];
        }
    }
    float partial = 0.0f;
    #pragma unroll
    for (int q = 0; q < 4; ++q) partial += W4[ch * 4 + q] * fmaxf(h3[q], 0.0f);
    if (active) p4s[ch * NPAIR + pl] = partial;
    __syncthreads();

    // Final: reduce 16 chunk-partials per pair, bias + mask
    if (t < NPAIR) {
        float sum = b4[0];
        #pragma unroll
        for (int c = 0; c < 16; ++c) sum += p4s[c * NPAIR + t];
        float dd = seld[t / TOPK][t % TOPK];
        out[blockIdx.x * NPAIR + t] = sum * ((dd <= 1.0f) ? 1.0f : 0.0f);
    }
}

// ---------------------------------------------------------------------------
extern "C" void kernel_launch(void* const* d_in, const int* in_sizes, int n_in,
                              void* d_out, int out_size, void* d_ws, size_t ws_size,
                              hipStream_t stream) {
    const float* x  = (const float*)d_in[0];
    const float* rp = (const float*)d_in[1];
    const float* W1 = (const float*)d_in[2];
    const float* b1 = (const float*)d_in[3];
    const float* W2 = (const float*)d_in[4];
    const float* b2 = (const float*)d_in[5];
    const float* W3 = (const float*)d_in[6];
    const float* b3 = (const float*)d_in[7];
    const float* W4 = (const float*)d_in[8];
    const float* b4 = (const float*)d_in[9];
    float* out = (float*)d_out;

    fused_cbf<<<NN / RPB, 1024, 0, stream>>>(x, rp, W1, b1, W2, b2,
                                             W3, b3, W4, b4, out);
}

// Round 6
// 487.467 us; speedup vs baseline: 1.1916x; 1.1916x over previous
//
#include <hip/hip_runtime.h>

// Problem constants: N=4096 agents, TOP_K=12, OBS_RADIUS=1.0
#define NN    4096
#define TOPK  12
#define NP    (NN * TOPK)        // 49152 pairs
// d_out layout (f32): out[0..NP), mask[NP..2NP), indices[2NP..) as (row, j)
#define OFF_MASK (NP)
#define OFF_IDX  (2 * NP)
#define RPB   4                  // rows per block
#define NPAIR (RPB * TOPK)       // 48 pairs per block

// ---------------------------------------------------------------------------
// Fused kernel: block = 1024 threads = 4 rows. Round-6 fixes vs round-5:
//  * __launch_bounds__(1024, 4): VGPR cap 128 (round-5's (1024,8) capped at
//    64 -> VGPR_Count=32, ~440 MB of scratch spill traffic, 313 us).
//  * Phase A loads float2 (x,y) instead of float4 — z,w unused for distance;
//    halves load-staging registers so all 16 loads stay in flight. Phase C
//    re-gathers the selected float4s (786 KB, L3-hot).
//  Phase A (per 256-thread row-group): wave-local u64 pops
//    (key = f32bits(s)<<32 | j : u64 order == (s,j) lexicographic).
//  Phase B: waves 0..3 bitonic-merge each row's 48 candidates, write
//    mask+indices, park (j,d) in LDS.
//  Phase C (MLP 6->64->128->64->1): lanes 0..47 = pairs, 16 waves = neuron
//    chunks via readfirstlane -> all weight addrs scalar (s_load + v_fmac).
// ---------------------------------------------------------------------------
__global__ __launch_bounds__(1024, 4) void fused_cbf(
        const float* __restrict__ x, const float* __restrict__ rp,
        const float* __restrict__ W1, const float* __restrict__ b1,
        const float* __restrict__ W2, const float* __restrict__ b2,
        const float* __restrict__ W3, const float* __restrict__ b3,
        const float* __restrict__ W4, const float* __restrict__ b4,
        float* __restrict__ out) {
    __shared__ unsigned long long cand[RPB][NPAIR];   // 1.5 KB
    __shared__ int   selj[RPB][TOPK];
    __shared__ float seld[RPB][TOPK];
    __shared__ float h1s[64 * NPAIR];                 // 12 KB
    __shared__ float h2s[128 * NPAIR];                // 24 KB
    __shared__ float p4s[16 * NPAIR];                 // 3 KB

    const int t    = threadIdx.x;
    const int r    = t >> 8;          // sub-row 0..3
    const int tt   = t & 255;         // thread-in-row
    const int lane = t & 63;
    const int wrow = tt >> 6;         // wave-in-row 0..3
    const int i    = blockIdx.x * RPB + r;

    // ---- Phase A: stage (float2 = x,y only) + wave-local top-12 pops ----
    const float2* x2 = (const float2*)x + ((size_t)i * NN) * 2;
    float s[16];
    #pragma unroll
    for (int k = 0; k < 16; ++k) {
        float2 v = x2[(((k << 8) + tt) << 1)];
        s[k] = v.x * v.x + v.y * v.y;
    }
    unsigned long long bk;
    {
        float bs = s[0]; int bj = tt;
        #pragma unroll
        for (int k = 1; k < 16; ++k) {
            int j = (k << 8) + tt;
            if (s[k] < bs) { bs = s[k]; bj = j; }
        }
        bk = ((unsigned long long)__float_as_uint(bs) << 32) | (unsigned)bj;
    }
    unsigned long long mykey = ~0ULL;
    for (int it = 0; it < TOPK; ++it) {
        unsigned long long vk = bk;
        #pragma unroll
        for (int off = 1; off < 64; off <<= 1) {
            unsigned long long ok = __shfl_xor(vk, off, 64);
            vk = (ok < vk) ? ok : vk;
        }
        if (lane == it) mykey = vk;
        int wj = (int)(vk & 0xffffffffULL);
        if ((wj & 63) == lane) {          // owner pops + recomputes proposal
            int kk = wj >> 8;
            #pragma unroll
            for (int k = 0; k < 16; ++k)
                if (k == kk) s[k] = 3.0e38f;
            float bs = s[0]; int bj = tt;
            #pragma unroll
            for (int k = 1; k < 16; ++k) {
                int j = (k << 8) + tt;
                if (s[k] < bs) { bs = s[k]; bj = j; }
            }
            bk = ((unsigned long long)__float_as_uint(bs) << 32) | (unsigned)bj;
        }
    }
    if (lane < TOPK) cand[r][wrow * TOPK + lane] = mykey;
    __syncthreads();

    // ---- Phase B: merge (waves 0..3 handle rows 0..3) ----
    {
        const int W = t >> 6;
        if (W < RPB) {
            unsigned long long key = (lane < NPAIR) ? cand[W][lane] : ~0ULL;
            #pragma unroll
            for (int k = 2; k <= 64; k <<= 1) {
                #pragma unroll
                for (int jj = k >> 1; jj >= 1; jj >>= 1) {
                    unsigned long long ok = __shfl_xor(key, jj, 64);
                    bool keepMin = ((lane & k) == 0) == ((lane & jj) == 0);
                    unsigned long long mn = (ok < key) ? ok : key;
                    unsigned long long mx = (ok < key) ? key : ok;
                    key = keepMin ? mn : mx;
                }
            }
            if (lane < TOPK) {
                int   j  = (int)(key & 0xffffffffULL);
                float ss = __uint_as_float((unsigned)(key >> 32));
                float d  = sqrtf(ss + 2.0e-4f);      // sqrt(sum(x[:2]^2+1e-4))
                int ii = blockIdx.x * RPB + W;
                int p  = ii * TOPK + lane;
                out[OFF_MASK + p]        = (d <= 1.0f) ? 1.0f : 0.0f;
                out[OFF_IDX + 2 * p]     = (float)ii;
                out[OFF_IDX + 2 * p + 1] = (float)j;
                selj[W][lane] = j;
                seld[W][lane] = d;
            }
        }
    }
    __syncthreads();

    // ---- Phase C: MLP. lanes 0..47 = pairs, 16 waves = neuron chunks ----
    const int  pl     = lane;
    const bool active = (pl < NPAIR);
    const int  ch     = __builtin_amdgcn_readfirstlane(t >> 6);  // SGPR 0..15
    const int  pls    = active ? pl : 0;       // clamped for LDS reads
    const int  pr     = pls / TOPK;
    const int  pk     = pls % TOPK;
    const int  jn     = selj[pr][pk];
    const float d     = seld[pr][pk];
    const int  ii     = blockIdx.x * RPB + pr;
    const float4 v = ((const float4*)x)[(size_t)ii * NN + jn];
    float xin[6];
    xin[0] = v.x; xin[1] = v.y; xin[2] = v.z; xin[3] = v.w;
    xin[4] = (ii == jn) ? 1.0f : 0.0f;
    xin[5] = d - rp[0];

    // L1: 4 neurons per wave (weights scalar)
    #pragma unroll
    for (int q = 0; q < 4; ++q) {
        int m = ch * 4 + q;
        const float* w = W1 + m * 6;
        float a = b1[m];
        #pragma unroll
        for (int c = 0; c < 6; ++c) a += w[c] * xin[c];
        if (active) h1s[m * NPAIR + pl] = fmaxf(a, 0.0f);
    }
    __syncthreads();

    // L2: 8 neurons per wave, k streamed in parts of 16
    float acc[8];
    #pragma unroll
    for (int q = 0; q < 8; ++q) acc[q] = b2[ch * 8 + q];
    for (int part = 0; part < 4; ++part) {
        float h1r[16];
        #pragma unroll
        for (int k = 0; k < 16; ++k) h1r[k] = h1s[(part * 16 + k) * NPAIR + pls];
        #pragma unroll
        for (int q = 0; q < 8; ++q) {
            const float* w = W2 + (ch * 8 + q) * 64 + part * 16;   // scalar
            #pragma unroll
            for (int k = 0; k < 16; ++k) acc[q] += w[k] * h1r[k];
        }
    }
    #pragma unroll
    for (int q = 0; q < 8; ++q)
        if (active) h2s[(ch * 8 + q) * NPAIR + pl] = fmaxf(acc[q], 0.0f);
    __syncthreads();

    // L3: 4 neurons per wave, k streamed in parts of 16; + L4 partial
    float h3[4];
    #pragma unroll
    for (int q = 0; q < 4; ++q) h3[q] = b3[ch * 4 + q];
    for (int part = 0; part < 8; ++part) {
        float h2r[16];
        #pragma unroll
        for (int k = 0; k < 16; ++k) h2r[k] = h2s[(part * 16 + k) * NPAIR + pls];
        #pragma unroll
        for (int q = 0; q < 4; ++q) {
            const float* w = W3 + (ch * 4 + q) * 128 + part * 16;  // scalar
            #pragma unroll
            for (int k = 0; k < 16; ++k) h3[q] += w[k] * h2r[k];
        }
    }
    float partial = 0.0f;
    #pragma unroll
    for (int q = 0; q < 4; ++q) partial += W4[ch * 4 + q] * fmaxf(h3[q], 0.0f);
    if (active) p4s[ch * NPAIR + pl] = partial;
    __syncthreads();

    // Final: reduce 16 chunk-partials per pair, bias + mask
    if (t < NPAIR) {
        float sum = b4[0];
        #pragma unroll
        for (int c = 0; c < 16; ++c) sum += p4s[c * NPAIR + t];
        float dd = seld[t / TOPK][t % TOPK];
        out[blockIdx.x * NPAIR + t] = sum * ((dd <= 1.0f) ? 1.0f : 0.0f);
    }
}

// ---------------------------------------------------------------------------
extern "C" void kernel_launch(void* const* d_in, const int* in_sizes, int n_in,
                              void* d_out, int out_size, void* d_ws, size_t ws_size,
                              hipStream_t stream) {
    const float* x  = (const float*)d_in[0];
    const float* rp = (const float*)d_in[1];
    const float* W1 = (const float*)d_in[2];
    const float* b1 = (const float*)d_in[3];
    const float* W2 = (const float*)d_in[4];
    const float* b2 = (const float*)d_in[5];
    const float* W3 = (const float*)d_in[6];
    const float* b3 = (const float*)d_in[7];
    const float* W4 = (const float*)d_in[8];
    const float* b4 = (const float*)d_in[9];
    float* out = (float*)d_out;

    fused_cbf<<<NN / RPB, 1024, 0, stream>>>(x, rp, W1, b1, W2, b2,
                                             W3, b3, W4, b4, out);
}